// Round 5
// baseline (541.179 us; speedup 1.0000x reference)
//
#include <hip/hip_runtime.h>
#include <math.h>

typedef __attribute__((ext_vector_type(8))) short short8;
typedef __attribute__((ext_vector_type(4))) float floatx4;

static __device__ __forceinline__ ushort f32_to_bf16_rne(float f) {
  union { float f; unsigned int i; } c;
  c.f = f;
  unsigned int lsb = (c.i >> 16) & 1u;
  c.i += 0x7fffu + lsb;
  return (ushort)(c.i >> 16);
}
static __device__ __forceinline__ float bf16_lo(unsigned int v) {
  union { unsigned int i; float f; } c;
  c.i = v << 16;
  return c.f;
}
static __device__ __forceinline__ float bf16_hi(unsigned int v) {
  union { unsigned int i; float f; } c;
  c.i = v & 0xffff0000u;
  return c.f;
}

// ---------------- graph build: 2-level locality-staged CSR ----------------
// bucket = dst >> 9 (512 nodes per bucket). NBLK chunks of edges.

#define NBLK 256

__global__ __launch_bounds__(256) void binhist_kernel(const int* __restrict__ dst,
                                                      int* __restrict__ bh, int E, int EBLK,
                                                      int NBUCKET) {
  __shared__ int h[256];
  int t = threadIdx.x, blk = blockIdx.x;
  h[t] = 0;
  __syncthreads();
  int e0 = blk * EBLK, e1 = min(E, e0 + EBLK);
  for (int e = e0 + t; e < e1; e += 256) atomicAdd(&h[__builtin_nontemporal_load(dst + e) >> 9], 1);
  __syncthreads();
  if (t < NBUCKET) bh[t * NBLK + blk] = h[t];
}

__global__ void scan1_kernel(const int* __restrict__ counts, int* __restrict__ offsets,
                             int* __restrict__ tileSums, int N) {
  __shared__ int sd[256];
  int t = threadIdx.x;
  int base = blockIdx.x * 1024 + t * 4;
  int v[4];
#pragma unroll
  for (int i = 0; i < 4; i++) v[i] = (base + i < N) ? counts[base + i] : 0;
  int s = v[0] + v[1] + v[2] + v[3];
  sd[t] = s;
  __syncthreads();
  int acc = s;
  for (int off = 1; off < 256; off <<= 1) {
    int add = (t >= off) ? sd[t - off] : 0;
    __syncthreads();
    acc += add;
    sd[t] = acc;
    __syncthreads();
  }
  int run = acc - s;
#pragma unroll
  for (int i = 0; i < 4; i++) {
    if (base + i < N) offsets[base + i] = run;
    run += v[i];
  }
  if (t == 255) tileSums[blockIdx.x] = acc;
}

__global__ void scan2_kernel(int* __restrict__ tileSums, int nT) {
  __shared__ int sd[128];
  int t = threadIdx.x;
  int v = (t < nT) ? tileSums[t] : 0;
  sd[t] = v;
  __syncthreads();
  int acc = v;
  for (int off = 1; off < 128; off <<= 1) {
    int add = (t >= off) ? sd[t - off] : 0;
    __syncthreads();
    acc += add;
    sd[t] = acc;
    __syncthreads();
  }
  if (t < nT) tileSums[t] = acc - v;
}

__global__ void scan3_nc_kernel(int* __restrict__ offsets, const int* __restrict__ tileSums,
                                int N) {
  int i = blockIdx.x * 256 + threadIdx.x;
  if (i >= N) return;
  offsets[i] += tileSums[i >> 10];
}

__global__ __launch_bounds__(256) void binscatter_kernel(const int* __restrict__ src,
                                                         const int* __restrict__ dst,
                                                         const int* __restrict__ bhOff,
                                                         int2* __restrict__ binned, int E,
                                                         int EBLK, int NBUCKET) {
  __shared__ int cur[256];
  int t = threadIdx.x, blk = blockIdx.x;
  if (t < NBUCKET) cur[t] = bhOff[t * NBLK + blk];
  __syncthreads();
  int e0 = blk * EBLK, e1 = min(E, e0 + EBLK);
  for (int e = e0 + t; e < e1; e += 256) {
    int d = __builtin_nontemporal_load(dst + e);
    int s = __builtin_nontemporal_load(src + e);
    int pos = atomicAdd(&cur[d >> 9], 1);
    binned[pos] = make_int2(s, d);
  }
}

__global__ __launch_bounds__(256) void bucket_build_kernel(
    const int2* __restrict__ binned, const int* __restrict__ bhOff, int* __restrict__ counts,
    int* __restrict__ offsets, int* __restrict__ csr, int N, int E, int NBUCKET) {
  __shared__ int h[512];
  __shared__ int lofs[512];
  __shared__ int cur[512];
  __shared__ int sd[256];
  int b = blockIdx.x, t = threadIdx.x;
  int S = bhOff[b * NBLK];
  int Send = (b + 1 < NBUCKET) ? bhOff[(b + 1) * NBLK] : E;
  h[t] = 0;
  h[t + 256] = 0;
  __syncthreads();
  for (int e = S + t; e < Send; e += 256) {
    long long rv = __builtin_nontemporal_load((const long long*)binned + e);
    atomicAdd(&h[(int)(rv >> 32) & 511], 1);
  }
  __syncthreads();
  int h0 = h[2 * t], h1 = h[2 * t + 1];
  int s = h0 + h1;
  sd[t] = s;
  __syncthreads();
  int acc = s;
  for (int off = 1; off < 256; off <<= 1) {
    int add = (t >= off) ? sd[t - off] : 0;
    __syncthreads();
    acc += add;
    sd[t] = acc;
    __syncthreads();
  }
  int run = acc - s;
  lofs[2 * t] = run;
  lofs[2 * t + 1] = run + h0;
  __syncthreads();
  int node0 = b * 512;
#pragma unroll
  for (int i = 0; i < 2; i++) {
    int l = t + i * 256;
    int node = node0 + l;
    if (node < N) {
      counts[node] = h[l];
      offsets[node] = S + lofs[l];
    }
    cur[l] = S + lofs[l];
  }
  __syncthreads();
  for (int e = S + t; e < Send; e += 256) {
    long long rv = __builtin_nontemporal_load((const long long*)binned + e);
    int pos = atomicAdd(&cur[(int)(rv >> 32) & 511], 1);
    csr[pos] = (int)(rv & 0xffffffff);
  }
}

// ---------------- conversions ----------------

// x (f32 row-major [N][128]) -> xt (bf16 sliced [8][N][16]); u32 view: xt[g][n][j], j=0..7
__global__ void x_to_xt_kernel(const float* __restrict__ x, unsigned int* __restrict__ xt, int N) {
  int idx = blockIdx.x * 256 + threadIdx.x;
  if (idx >= N * 64) return;
  int n = idx >> 6, q = idx & 63;
  int g = q >> 3, j = q & 7;
  float a = x[(size_t)n * 128 + q * 2];
  float b = x[(size_t)n * 128 + q * 2 + 1];
  unsigned int r = (unsigned int)f32_to_bf16_rne(a) | ((unsigned int)f32_to_bf16_rne(b) << 16);
  xt[(size_t)g * N * 8 + (size_t)n * 8 + j] = r;
}

// WT[c][k] = bf16(W[k][c])
__global__ void wt_conv_kernel(const float* __restrict__ W, ushort* __restrict__ WT, int K, int C) {
  int idx = blockIdx.x * 256 + threadIdx.x;
  if (idx >= K * C) return;
  int k = idx / C, c = idx % C;
  WT[(size_t)c * K + k] = f32_to_bf16_rne(W[idx]);
}

// ---------------- aggregation: segment max, dim-sliced + XCD-local ----------------
// block handles group g = blockIdx&7, 32 nodes (4 waves x 8 nodes).
// lane = (node_slot<<3)|j ; per edge loads 32B slice of src row for its node.

__global__ __launch_bounds__(256) void agg_max_xt_kernel(
    const unsigned int* __restrict__ xt, const int* __restrict__ csr,
    const int* __restrict__ offsets, const int* __restrict__ counts,
    unsigned int* __restrict__ aggt, int N) {
  int t = threadIdx.x;
  int b = blockIdx.x;
  int g = b & 7;
  int chunk = b >> 3;
  int lane = t & 63;
  int wid = t >> 6;
  int slot = lane >> 3;
  int j = lane & 7;
  int node = chunk * 32 + wid * 8 + slot;
  if (node >= N) return;
  const unsigned int* base = xt + (size_t)g * N * 8;
  int start = offsets[node];
  int deg = counts[node];
  float m0 = 0.0f, m1 = 0.0f;  // PyG scatter-max: 0 for isolated nodes
  if (deg > 0) {
    m0 = -INFINITY;
    m1 = -INFINITY;
    int e = 0;
    for (; e + 4 <= deg; e += 4) {
      int s0 = __builtin_nontemporal_load(csr + start + e + 0);
      int s1 = __builtin_nontemporal_load(csr + start + e + 1);
      int s2 = __builtin_nontemporal_load(csr + start + e + 2);
      int s3 = __builtin_nontemporal_load(csr + start + e + 3);
      unsigned int v0 = base[(size_t)s0 * 8 + j];
      unsigned int v1 = base[(size_t)s1 * 8 + j];
      unsigned int v2 = base[(size_t)s2 * 8 + j];
      unsigned int v3 = base[(size_t)s3 * 8 + j];
      m0 = fmaxf(m0, fmaxf(fmaxf(bf16_lo(v0), bf16_lo(v1)), fmaxf(bf16_lo(v2), bf16_lo(v3))));
      m1 = fmaxf(m1, fmaxf(fmaxf(bf16_hi(v0), bf16_hi(v1)), fmaxf(bf16_hi(v2), bf16_hi(v3))));
    }
    for (; e < deg; e++) {
      unsigned int v = base[(size_t)__builtin_nontemporal_load(csr + start + e) * 8 + j];
      m0 = fmaxf(m0, bf16_lo(v));
      m1 = fmaxf(m1, bf16_hi(v));
    }
  }
  unsigned int res = (__float_as_uint(m0) >> 16) | (__float_as_uint(m1) & 0xffff0000u);
  aggt[(size_t)g * N * 8 + (size_t)node * 8 + j] = res;
}

// ---------------- fused dual-GEMM (MFMA bf16) + bias + L2 normalize (+ ReLU) ----------------
// A, X in sliced layout [8][N][16] bf16. k-octet (kc,lk): g=2*kc+(lk>>1), off=(lk&1)*8.
// OUTBF16 path writes out in sliced layout (group = ct since DOUT=128).

template <int DOUT, bool RELU, bool OUTBF16>
__global__ __launch_bounds__(256) void gemm_mfma_kernel(
    const ushort* __restrict__ A, const ushort* __restrict__ X, const ushort* __restrict__ WlT,
    const ushort* __restrict__ WrT, const float* __restrict__ bias, void* __restrict__ outp,
    int N) {
  constexpr int D = 128;
  constexpr int NCT = DOUT / 16;
  int t = threadIdx.x;
  int lane = t & 63;
  int wid = t >> 6;
  int l16 = lane & 15;
  int lk = lane >> 4;
  int rowbase = blockIdx.x * 128 + wid * 32;

  floatx4 acc[2][NCT];
#pragma unroll
  for (int rt = 0; rt < 2; rt++)
#pragma unroll
    for (int ct = 0; ct < NCT; ct++) acc[rt][ct] = (floatx4){0.f, 0.f, 0.f, 0.f};

  int ra = rowbase + l16;       if (ra > N - 1) ra = N - 1;
  int rb = rowbase + 16 + l16;  if (rb > N - 1) rb = N - 1;

  size_t sliceN = (size_t)N * 16;
  int goff = (lk & 1) * 8;

#pragma unroll
  for (int kc = 0; kc < 4; kc++) {
    int g = kc * 2 + (lk >> 1);
    size_t sbase = (size_t)g * sliceN + goff;
    short8 a0 = *(const short8*)(A + sbase + (size_t)ra * 16);
    short8 a1 = *(const short8*)(A + sbase + (size_t)rb * 16);
    short8 x0 = *(const short8*)(X + sbase + (size_t)ra * 16);
    short8 x1 = *(const short8*)(X + sbase + (size_t)rb * 16);
    int ko = kc * 32 + lk * 8;
#pragma unroll
    for (int ct = 0; ct < NCT; ct++) {
      int c = ct * 16 + l16;
      short8 bl = *(const short8*)(WlT + (size_t)c * D + ko);
      short8 br = *(const short8*)(WrT + (size_t)c * D + ko);
      acc[0][ct] = __builtin_amdgcn_mfma_f32_16x16x32_bf16(a0, bl, acc[0][ct], 0, 0, 0);
      acc[0][ct] = __builtin_amdgcn_mfma_f32_16x16x32_bf16(x0, br, acc[0][ct], 0, 0, 0);
      acc[1][ct] = __builtin_amdgcn_mfma_f32_16x16x32_bf16(a1, bl, acc[1][ct], 0, 0, 0);
      acc[1][ct] = __builtin_amdgcn_mfma_f32_16x16x32_bf16(x1, br, acc[1][ct], 0, 0, 0);
    }
  }

  float bb[NCT];
#pragma unroll
  for (int ct = 0; ct < NCT; ct++) bb[ct] = bias[ct * 16 + l16];
#pragma unroll
  for (int rt = 0; rt < 2; rt++)
#pragma unroll
    for (int ct = 0; ct < NCT; ct++)
#pragma unroll
      for (int r = 0; r < 4; r++) acc[rt][ct][r] += bb[ct];

#pragma unroll
  for (int rt = 0; rt < 2; rt++) {
#pragma unroll
    for (int r = 0; r < 4; r++) {
      float ss = 0.f;
#pragma unroll
      for (int ct = 0; ct < NCT; ct++) ss += acc[rt][ct][r] * acc[rt][ct][r];
      ss += __shfl_xor(ss, 1);
      ss += __shfl_xor(ss, 2);
      ss += __shfl_xor(ss, 4);
      ss += __shfl_xor(ss, 8);
      float inv = 1.0f / fmaxf(sqrtf(ss), 1e-12f);
      int n = rowbase + rt * 16 + lk * 4 + r;
      if (n < N) {
#pragma unroll
        for (int ct = 0; ct < NCT; ct++) {
          float v = acc[rt][ct][r] * inv;
          if (RELU) v = fmaxf(v, 0.f);
          if (OUTBF16) {
            // sliced layout: group = ct (16 cols per group), within-offset l16
            ((ushort*)outp)[(size_t)ct * sliceN + (size_t)n * 16 + l16] = f32_to_bf16_rne(v);
          } else {
            ((float*)outp)[(size_t)n * DOUT + ct * 16 + l16] = v;
          }
        }
      }
    }
  }
}

// ---------------- launch ----------------

extern "C" void kernel_launch(void* const* d_in, const int* in_sizes, int n_in, void* d_out,
                              int out_size, void* d_ws, size_t ws_size, hipStream_t stream) {
  const float* x = (const float*)d_in[0];
  const int* ei = (const int*)d_in[1];
  const float* Wl1 = (const float*)d_in[2];
  const float* Wr1 = (const float*)d_in[3];
  const float* b1 = (const float*)d_in[4];
  const float* Wl2 = (const float*)d_in[5];
  const float* Wr2 = (const float*)d_in[6];
  const float* b2 = (const float*)d_in[7];
  float* out = (float*)d_out;

  const int E = in_sizes[1] / 2;
  const int N = in_sizes[0] / 128;
  const int D = 128;

  const int* src = ei;
  const int* dst = ei + E;

  char* w = (char*)d_ws;
  size_t off = 0;
  auto alloc = [&](size_t bytes) {
    void* p = w + off;
    off = (off + bytes + 511) & ~((size_t)511);
    return p;
  };
  const int NBUCKET = (N + 511) >> 9;
  const int M = NBUCKET * NBLK;
  int* bh = (int*)alloc((size_t)M * 4);
  int* tileSums = (int*)alloc(512);
  int* counts = (int*)alloc((size_t)N * 4);
  int* offsets = (int*)alloc((size_t)N * 4);
  int2* binned = (int2*)alloc((size_t)E * 8);
  int* csr = (int*)alloc((size_t)E * 4);
  ushort* xbt = (ushort*)alloc((size_t)N * D * 2);
  ushort* aggt = (ushort*)alloc((size_t)N * D * 2);
  ushort* hbt = (ushort*)alloc((size_t)N * D * 2);
  ushort* WlT1 = (ushort*)alloc(128 * 128 * 2);
  ushort* WrT1 = (ushort*)alloc(128 * 128 * 2);
  ushort* WlT2 = (ushort*)alloc(128 * 64 * 2);
  ushort* WrT2 = (ushort*)alloc(128 * 64 * 2);
  (void)ws_size;

  const int EBLK = (E + NBLK - 1) / NBLK;
  const int nTiles = (M + 1023) / 1024;

  // graph build (reused by both layers)
  binhist_kernel<<<NBLK, 256, 0, stream>>>(dst, bh, E, EBLK, NBUCKET);
  scan1_kernel<<<nTiles, 256, 0, stream>>>(bh, bh, tileSums, M);
  scan2_kernel<<<1, 128, 0, stream>>>(tileSums, nTiles);
  scan3_nc_kernel<<<(M + 255) / 256, 256, 0, stream>>>(bh, tileSums, M);
  binscatter_kernel<<<NBLK, 256, 0, stream>>>(src, dst, bh, binned, E, EBLK, NBUCKET);
  bucket_build_kernel<<<NBUCKET, 256, 0, stream>>>(binned, bh, counts, offsets, csr, N, E,
                                                   NBUCKET);

  // conversions
  x_to_xt_kernel<<<(N * 64 + 255) / 256, 256, 0, stream>>>(x, (unsigned int*)xbt, N);
  wt_conv_kernel<<<(128 * 128 + 255) / 256, 256, 0, stream>>>(Wl1, WlT1, 128, 128);
  wt_conv_kernel<<<(128 * 128 + 255) / 256, 256, 0, stream>>>(Wr1, WrT1, 128, 128);
  wt_conv_kernel<<<(128 * 64 + 255) / 256, 256, 0, stream>>>(Wl2, WlT2, 128, 64);
  wt_conv_kernel<<<(128 * 64 + 255) / 256, 256, 0, stream>>>(Wr2, WrT2, 128, 64);

  const int nbAgg = ((N + 31) / 32) * 8;  // group = blockIdx & 7
  const int nbGemm = (N + 127) / 128;

  // layer 1
  agg_max_xt_kernel<<<nbAgg, 256, 0, stream>>>((const unsigned int*)xbt, csr, offsets, counts,
                                               (unsigned int*)aggt, N);
  gemm_mfma_kernel<128, true, true>
      <<<nbGemm, 256, 0, stream>>>(aggt, xbt, WlT1, WrT1, b1, hbt, N);

  // layer 2
  agg_max_xt_kernel<<<nbAgg, 256, 0, stream>>>((const unsigned int*)hbt, csr, offsets, counts,
                                               (unsigned int*)aggt, N);
  gemm_mfma_kernel<64, false, false>
      <<<nbGemm, 256, 0, stream>>>(aggt, hbt, WlT2, WrT2, b2, out, N);
}

// Round 6
// 361.470 us; speedup vs baseline: 1.4972x; 1.4972x over previous
//
#include <hip/hip_runtime.h>
#include <math.h>

typedef __attribute__((ext_vector_type(8))) short short8;
typedef __attribute__((ext_vector_type(4))) float floatx4;

static __device__ __forceinline__ ushort f32_to_bf16_rne(float f) {
  union { float f; unsigned int i; } c;
  c.f = f;
  unsigned int lsb = (c.i >> 16) & 1u;
  c.i += 0x7fffu + lsb;
  return (ushort)(c.i >> 16);
}
static __device__ __forceinline__ float bf16_lo(unsigned int v) {
  union { unsigned int i; float f; } c;
  c.i = v << 16;
  return c.f;
}
static __device__ __forceinline__ float bf16_hi(unsigned int v) {
  union { unsigned int i; float f; } c;
  c.i = v & 0xffff0000u;
  return c.f;
}

// ---------------- graph build: 2-level locality-staged CSR ----------------
// bucket = dst >> 9 (512 nodes per bucket). NBLK chunks of edges.
// binned record: u32 = (dst & 511) << 17 | src   (requires N < 2^17 = 131072)

#define NBLK 256

__global__ __launch_bounds__(256) void binhist_kernel(const int* __restrict__ dst,
                                                      int* __restrict__ bh, int E, int EBLK,
                                                      int NBUCKET) {
  __shared__ int h[256];
  int t = threadIdx.x, blk = blockIdx.x;
  h[t] = 0;
  __syncthreads();
  int e0 = blk * EBLK, e1 = min(E, e0 + EBLK);
  for (int e = e0 + t; e < e1; e += 256) atomicAdd(&h[__builtin_nontemporal_load(dst + e) >> 9], 1);
  __syncthreads();
  if (t < NBUCKET) bh[t * NBLK + blk] = h[t];
}

__global__ void scan1_kernel(const int* __restrict__ counts, int* __restrict__ offsets,
                             int* __restrict__ tileSums, int N) {
  __shared__ int sd[256];
  int t = threadIdx.x;
  int base = blockIdx.x * 1024 + t * 4;
  int v[4];
#pragma unroll
  for (int i = 0; i < 4; i++) v[i] = (base + i < N) ? counts[base + i] : 0;
  int s = v[0] + v[1] + v[2] + v[3];
  sd[t] = s;
  __syncthreads();
  int acc = s;
  for (int off = 1; off < 256; off <<= 1) {
    int add = (t >= off) ? sd[t - off] : 0;
    __syncthreads();
    acc += add;
    sd[t] = acc;
    __syncthreads();
  }
  int run = acc - s;
#pragma unroll
  for (int i = 0; i < 4; i++) {
    if (base + i < N) offsets[base + i] = run;
    run += v[i];
  }
  if (t == 255) tileSums[blockIdx.x] = acc;
}

__global__ void scan2_kernel(int* __restrict__ tileSums, int nT) {
  __shared__ int sd[128];
  int t = threadIdx.x;
  int v = (t < nT) ? tileSums[t] : 0;
  sd[t] = v;
  __syncthreads();
  int acc = v;
  for (int off = 1; off < 128; off <<= 1) {
    int add = (t >= off) ? sd[t - off] : 0;
    __syncthreads();
    acc += add;
    sd[t] = acc;
    __syncthreads();
  }
  if (t < nT) tileSums[t] = acc - v;
}

__global__ void scan3_nc_kernel(int* __restrict__ offsets, const int* __restrict__ tileSums,
                                int N) {
  int i = blockIdx.x * 256 + threadIdx.x;
  if (i >= N) return;
  offsets[i] += tileSums[i >> 10];
}

__global__ __launch_bounds__(256) void binscatter_kernel(const int* __restrict__ src,
                                                         const int* __restrict__ dst,
                                                         const int* __restrict__ bhOff,
                                                         unsigned int* __restrict__ binned, int E,
                                                         int EBLK, int NBUCKET) {
  __shared__ int cur[256];
  int t = threadIdx.x, blk = blockIdx.x;
  if (t < NBUCKET) cur[t] = bhOff[t * NBLK + blk];
  __syncthreads();
  int e0 = blk * EBLK, e1 = min(E, e0 + EBLK);
  for (int e = e0 + t; e < e1; e += 256) {
    int d = __builtin_nontemporal_load(dst + e);
    int s = __builtin_nontemporal_load(src + e);
    int pos = atomicAdd(&cur[d >> 9], 1);
    binned[pos] = ((unsigned int)(d & 511) << 17) | (unsigned int)s;
  }
}

__global__ __launch_bounds__(256) void bucket_build_kernel(
    const unsigned int* __restrict__ binned, const int* __restrict__ bhOff,
    int* __restrict__ counts, int* __restrict__ offsets, int* __restrict__ csr, int N, int E,
    int NBUCKET) {
  __shared__ int h[512];
  __shared__ int lofs[512];
  __shared__ int cur[512];
  __shared__ int sd[256];
  int b = blockIdx.x, t = threadIdx.x;
  int S = bhOff[b * NBLK];
  int Send = (b + 1 < NBUCKET) ? bhOff[(b + 1) * NBLK] : E;
  h[t] = 0;
  h[t + 256] = 0;
  __syncthreads();
  for (int e = S + t; e < Send; e += 256) {
    unsigned int rv = __builtin_nontemporal_load(binned + e);
    atomicAdd(&h[(rv >> 17) & 511], 1);
  }
  __syncthreads();
  int h0 = h[2 * t], h1 = h[2 * t + 1];
  int s = h0 + h1;
  sd[t] = s;
  __syncthreads();
  int acc = s;
  for (int off = 1; off < 256; off <<= 1) {
    int add = (t >= off) ? sd[t - off] : 0;
    __syncthreads();
    acc += add;
    sd[t] = acc;
    __syncthreads();
  }
  int run = acc - s;
  lofs[2 * t] = run;
  lofs[2 * t + 1] = run + h0;
  __syncthreads();
  int node0 = b * 512;
#pragma unroll
  for (int i = 0; i < 2; i++) {
    int l = t + i * 256;
    int node = node0 + l;
    if (node < N) {
      counts[node] = h[l];
      offsets[node] = S + lofs[l];
    }
    cur[l] = S + lofs[l];
  }
  __syncthreads();
  for (int e = S + t; e < Send; e += 256) {
    unsigned int rv = __builtin_nontemporal_load(binned + e);
    int pos = atomicAdd(&cur[(rv >> 17) & 511], 1);
    csr[pos] = (int)(rv & 0x1ffffu);
  }
}

// ---------------- conversions ----------------

__global__ void f32_to_bf16_kernel(const float* __restrict__ in, ushort* __restrict__ out, int n) {
  int i = (blockIdx.x * 256 + threadIdx.x) * 8;
  if (i >= n) return;
  float4 a = *(const float4*)(in + i);
  float4 b = *(const float4*)(in + i + 4);
  union { ushort u[8]; short8 v; } r;
  r.u[0] = f32_to_bf16_rne(a.x); r.u[1] = f32_to_bf16_rne(a.y);
  r.u[2] = f32_to_bf16_rne(a.z); r.u[3] = f32_to_bf16_rne(a.w);
  r.u[4] = f32_to_bf16_rne(b.x); r.u[5] = f32_to_bf16_rne(b.y);
  r.u[6] = f32_to_bf16_rne(b.z); r.u[7] = f32_to_bf16_rne(b.w);
  *(short8*)(out + i) = r.v;
}

// all four weight transposes in one launch. WT[c][k] = bf16(W[k][c]), K=128 always.
__global__ void wt_conv_all_kernel(const float* __restrict__ Wl1, const float* __restrict__ Wr1,
                                   const float* __restrict__ Wl2, const float* __restrict__ Wr2,
                                   ushort* __restrict__ WlT1, ushort* __restrict__ WrT1,
                                   ushort* __restrict__ WlT2, ushort* __restrict__ WrT2) {
  int idx = blockIdx.x * 256 + threadIdx.x;  // 0..49151
  const float* W;
  ushort* WT;
  int C, base;
  if (idx < 16384)      { W = Wl1; WT = WlT1; C = 128; base = idx; }
  else if (idx < 32768) { W = Wr1; WT = WrT1; C = 128; base = idx - 16384; }
  else if (idx < 40960) { W = Wl2; WT = WlT2; C = 64;  base = idx - 32768; }
  else                  { W = Wr2; WT = WrT2; C = 64;  base = idx - 40960; }
  int k = base / C, c = base % C;
  WT[c * 128 + k] = f32_to_bf16_rne(W[base]);
}

// ---------------- aggregation: segment max (bf16 rows, 256B each) ----------------
// one wave per node; lane owns 2 bf16 dims packed in one u32.
// node/start/deg/csr are wave-uniform: readfirstlane forces the scalar path
// (s_load index stream, saddr-form feature gathers, SALU loop control).

__global__ __launch_bounds__(256) void agg_max_bf16_kernel(
    const ushort* __restrict__ feat, const int* __restrict__ csr,
    const int* __restrict__ offsets, const int* __restrict__ counts,
    unsigned int* __restrict__ aggb, int N) {
  int lane = threadIdx.x & 63;
  int node = __builtin_amdgcn_readfirstlane((int)((blockIdx.x * 256 + threadIdx.x) >> 6));
  if (node >= N) return;
  const unsigned int* fu = (const unsigned int*)feat;
  int start = offsets[node];
  int deg = counts[node];
  float m0 = 0.0f, m1 = 0.0f;  // PyG scatter-max: 0 for isolated nodes
  if (deg > 0) {
    m0 = -INFINITY;
    m1 = -INFINITY;
    const int* ce = csr + start;
    int e = 0;
    for (; e + 8 <= deg; e += 8) {
      int s0 = ce[e + 0], s1 = ce[e + 1], s2 = ce[e + 2], s3 = ce[e + 3];
      int s4 = ce[e + 4], s5 = ce[e + 5], s6 = ce[e + 6], s7 = ce[e + 7];
      unsigned int v0 = fu[(size_t)s0 * 64 + lane];
      unsigned int v1 = fu[(size_t)s1 * 64 + lane];
      unsigned int v2 = fu[(size_t)s2 * 64 + lane];
      unsigned int v3 = fu[(size_t)s3 * 64 + lane];
      unsigned int v4 = fu[(size_t)s4 * 64 + lane];
      unsigned int v5 = fu[(size_t)s5 * 64 + lane];
      unsigned int v6 = fu[(size_t)s6 * 64 + lane];
      unsigned int v7 = fu[(size_t)s7 * 64 + lane];
      m0 = fmaxf(m0, fmaxf(fmaxf(bf16_lo(v0), bf16_lo(v1)), fmaxf(bf16_lo(v2), bf16_lo(v3))));
      m0 = fmaxf(m0, fmaxf(fmaxf(bf16_lo(v4), bf16_lo(v5)), fmaxf(bf16_lo(v6), bf16_lo(v7))));
      m1 = fmaxf(m1, fmaxf(fmaxf(bf16_hi(v0), bf16_hi(v1)), fmaxf(bf16_hi(v2), bf16_hi(v3))));
      m1 = fmaxf(m1, fmaxf(fmaxf(bf16_hi(v4), bf16_hi(v5)), fmaxf(bf16_hi(v6), bf16_hi(v7))));
    }
    for (; e < deg; e++) {
      unsigned int v = fu[(size_t)ce[e] * 64 + lane];
      m0 = fmaxf(m0, bf16_lo(v));
      m1 = fmaxf(m1, bf16_hi(v));
    }
  }
  // m0/m1 are exact bf16 values (or 0) -> truncation is exact
  unsigned int res = (__float_as_uint(m0) >> 16) | (__float_as_uint(m1) & 0xffff0000u);
  aggb[(size_t)node * 64 + lane] = res;
}

// ---------------- fused dual-GEMM (MFMA bf16) + bias + L2 normalize (+ ReLU) ----------------
// Row-major bf16 A/X [N][128]; WT[c][k] transposed weights. No LDS.
// A frags: lane&15 = row, lane>>4 = k-octet. C/D: col=ct*16+l16, row=rt*16+lk*4+reg.

template <int DOUT, bool RELU, bool OUTBF16>
__global__ __launch_bounds__(256) void gemm_mfma_kernel(
    const ushort* __restrict__ A, const ushort* __restrict__ X, const ushort* __restrict__ WlT,
    const ushort* __restrict__ WrT, const float* __restrict__ bias, void* __restrict__ outp,
    int N) {
  constexpr int D = 128;
  constexpr int NCT = DOUT / 16;
  int t = threadIdx.x;
  int lane = t & 63;
  int wid = t >> 6;
  int l16 = lane & 15;
  int lk = lane >> 4;
  int rowbase = blockIdx.x * 128 + wid * 32;

  floatx4 acc[2][NCT];
#pragma unroll
  for (int rt = 0; rt < 2; rt++)
#pragma unroll
    for (int ct = 0; ct < NCT; ct++) acc[rt][ct] = (floatx4){0.f, 0.f, 0.f, 0.f};

  int ra = rowbase + l16;       if (ra > N - 1) ra = N - 1;
  int rb = rowbase + 16 + l16;  if (rb > N - 1) rb = N - 1;
  const ushort* pA0 = A + (size_t)ra * D;
  const ushort* pA1 = A + (size_t)rb * D;
  const ushort* pX0 = X + (size_t)ra * D;
  const ushort* pX1 = X + (size_t)rb * D;

#pragma unroll
  for (int kc = 0; kc < 4; kc++) {
    int ko = kc * 32 + lk * 8;
    short8 a0 = *(const short8*)(pA0 + ko);
    short8 a1 = *(const short8*)(pA1 + ko);
    short8 x0 = *(const short8*)(pX0 + ko);
    short8 x1 = *(const short8*)(pX1 + ko);
#pragma unroll
    for (int ct = 0; ct < NCT; ct++) {
      int c = ct * 16 + l16;
      short8 bl = *(const short8*)(WlT + (size_t)c * D + ko);
      short8 br = *(const short8*)(WrT + (size_t)c * D + ko);
      acc[0][ct] = __builtin_amdgcn_mfma_f32_16x16x32_bf16(a0, bl, acc[0][ct], 0, 0, 0);
      acc[0][ct] = __builtin_amdgcn_mfma_f32_16x16x32_bf16(x0, br, acc[0][ct], 0, 0, 0);
      acc[1][ct] = __builtin_amdgcn_mfma_f32_16x16x32_bf16(a1, bl, acc[1][ct], 0, 0, 0);
      acc[1][ct] = __builtin_amdgcn_mfma_f32_16x16x32_bf16(x1, br, acc[1][ct], 0, 0, 0);
    }
  }

  float bb[NCT];
#pragma unroll
  for (int ct = 0; ct < NCT; ct++) bb[ct] = bias[ct * 16 + l16];
#pragma unroll
  for (int rt = 0; rt < 2; rt++)
#pragma unroll
    for (int ct = 0; ct < NCT; ct++)
#pragma unroll
      for (int r = 0; r < 4; r++) acc[rt][ct][r] += bb[ct];

#pragma unroll
  for (int rt = 0; rt < 2; rt++) {
#pragma unroll
    for (int r = 0; r < 4; r++) {
      float ss = 0.f;
#pragma unroll
      for (int ct = 0; ct < NCT; ct++) ss += acc[rt][ct][r] * acc[rt][ct][r];
      ss += __shfl_xor(ss, 1);
      ss += __shfl_xor(ss, 2);
      ss += __shfl_xor(ss, 4);
      ss += __shfl_xor(ss, 8);
      float inv = 1.0f / fmaxf(sqrtf(ss), 1e-12f);
      int n = rowbase + rt * 16 + lk * 4 + r;
      if (n < N) {
#pragma unroll
        for (int ct = 0; ct < NCT; ct++) {
          float v = acc[rt][ct][r] * inv;
          if (RELU) v = fmaxf(v, 0.f);
          size_t o = (size_t)n * DOUT + ct * 16 + l16;
          if (OUTBF16)
            ((ushort*)outp)[o] = f32_to_bf16_rne(v);
          else
            ((float*)outp)[o] = v;
        }
      }
    }
  }
}

// ---------------- launch ----------------

extern "C" void kernel_launch(void* const* d_in, const int* in_sizes, int n_in, void* d_out,
                              int out_size, void* d_ws, size_t ws_size, hipStream_t stream) {
  const float* x = (const float*)d_in[0];
  const int* ei = (const int*)d_in[1];
  const float* Wl1 = (const float*)d_in[2];
  const float* Wr1 = (const float*)d_in[3];
  const float* b1 = (const float*)d_in[4];
  const float* Wl2 = (const float*)d_in[5];
  const float* Wr2 = (const float*)d_in[6];
  const float* b2 = (const float*)d_in[7];
  float* out = (float*)d_out;

  const int E = in_sizes[1] / 2;
  const int N = in_sizes[0] / 128;
  const int D = 128;

  const int* src = ei;
  const int* dst = ei + E;

  char* w = (char*)d_ws;
  size_t off = 0;
  auto alloc = [&](size_t bytes) {
    void* p = w + off;
    off = (off + bytes + 511) & ~((size_t)511);
    return p;
  };
  const int NBUCKET = (N + 511) >> 9;
  const int M = NBUCKET * NBLK;
  int* bh = (int*)alloc((size_t)M * 4);
  int* tileSums = (int*)alloc(512);
  int* counts = (int*)alloc((size_t)N * 4);
  int* offsets = (int*)alloc((size_t)N * 4);
  unsigned int* binned = (unsigned int*)alloc((size_t)E * 4);
  int* csr = (int*)alloc((size_t)E * 4);
  ushort* xb = (ushort*)alloc((size_t)N * D * 2);
  ushort* aggb = (ushort*)alloc((size_t)N * D * 2);
  ushort* hb = (ushort*)alloc((size_t)N * D * 2);
  ushort* WlT1 = (ushort*)alloc(128 * 128 * 2);
  ushort* WrT1 = (ushort*)alloc(128 * 128 * 2);
  ushort* WlT2 = (ushort*)alloc(128 * 64 * 2);
  ushort* WrT2 = (ushort*)alloc(128 * 64 * 2);
  (void)ws_size;

  const int EBLK = (E + NBLK - 1) / NBLK;
  const int nTiles = (M + 1023) / 1024;

  // graph build (reused by both layers)
  binhist_kernel<<<NBLK, 256, 0, stream>>>(dst, bh, E, EBLK, NBUCKET);
  scan1_kernel<<<nTiles, 256, 0, stream>>>(bh, bh, tileSums, M);
  scan2_kernel<<<1, 128, 0, stream>>>(tileSums, nTiles);
  scan3_nc_kernel<<<(M + 255) / 256, 256, 0, stream>>>(bh, tileSums, M);
  binscatter_kernel<<<NBLK, 256, 0, stream>>>(src, dst, bh, binned, E, EBLK, NBUCKET);
  bucket_build_kernel<<<NBUCKET, 256, 0, stream>>>(binned, bh, counts, offsets, csr, N, E,
                                                   NBUCKET);

  // conversions
  f32_to_bf16_kernel<<<(N * D / 8 + 255) / 256, 256, 0, stream>>>(x, xb, N * D);
  wt_conv_all_kernel<<<192, 256, 0, stream>>>(Wl1, Wr1, Wl2, Wr2, WlT1, WrT1, WlT2, WrT2);

  const int nbGemm = (N + 127) / 128;

  // layer 1
  agg_max_bf16_kernel<<<(N * 64 + 255) / 256, 256, 0, stream>>>(xb, csr, offsets, counts,
                                                                (unsigned int*)aggb, N);
  gemm_mfma_kernel<128, true, true>
      <<<nbGemm, 256, 0, stream>>>(aggb, xb, WlT1, WrT1, b1, hb, N);

  // layer 2
  agg_max_bf16_kernel<<<(N * 64 + 255) / 256, 256, 0, stream>>>(hb, csr, offsets, counts,
                                                                (unsigned int*)aggb, N);
  gemm_mfma_kernel<64, false, false>
      <<<nbGemm, 256, 0, stream>>>(aggb, hb, WlT2, WrT2, b2, out, N);
}